// Round 5
// baseline (2210.383 us; speedup 1.0000x reference)
//
#include <hip/hip_runtime.h>
#include <hip/hip_bf16.h>

// Elman RNN: B=128, T=256, I=512, H=1024
//   Phase 1: xp[b,h] per t  (MFMA GEMM, bf16, 32x128 tiles)
//   Phase 2: ONE persistent kernel, 256 steps, EPOCH-STAMPED exchange:
//     - 8 independent batch-group chains (16 rows), 8 blocks/group (128 cols).
//     - h exchanged as stamped 8B atomic slots (epoch<<32)|2xbf16: the spin
//       load IS the data load -> no producer drain, no counter RMW, no
//       separate h-load RTT. One store-flight + one detect per step.
//     - R2 failed: serial per-slot spins (32 serialized RTTs). R3 failed:
//       bare launch_bounds -> 128-VGPR cap -> wfrag spilled (FETCH 600MB).
//       Fix: batched sweep w/ immediate scatter + (512,2) bound (R4-proven:
//       wfrag lands in AGPRs; VGPR_Count excludes AGPRs).
//     - s_sleep(1) throttle between sweep passes (anti-congestion).
//     - padded-pitch LDS (R4-proven: conflicts 1.78e7 -> 1.05e6).
// Precision: bf16 inputs, fp32 MFMA accumulate, fp32 tanh, fp32 output.

#define B_SZ 128
#define T_SZ 256
#define I_SZ 512
#define H_SZ 1024

#define GROUPS 8
#define CHUNKS 8                       // blocks per group (128 cols each)
#define GRID_P (GROUPS * CHUNKS)       // 64 persistent blocks
#define THR_P  512                     // 8 waves: 16 cols x K=1024 each
#define PITCH  2080                    // LDS row pitch (2048 + 32 pad)
#define SLOTS_PER_CHUNK 1024           // 16 rows x 64 col-pairs
#define SLOTS_PER_GROUP (CHUNKS * SLOTS_PER_CHUNK)   // 8192 (64 KB stamped)
#define BUF_U64 (GROUPS * SLOTS_PER_GROUP)           // 65536 u64 = 512 KB

typedef __bf16 bf16x8 __attribute__((ext_vector_type(8)));
typedef __bf16 bf16x4 __attribute__((ext_vector_type(4)));
typedef float f32x4 __attribute__((ext_vector_type(4)));
typedef unsigned long long u64;

__device__ __forceinline__ float fast_tanh(float x) {
    // exact at +-inf saturation, ~1e-6 abs err; bf16 noise dominates anyway
    return 1.0f - 2.0f / (__expf(2.0f * x) + 1.0f);
}

__device__ __forceinline__ unsigned pack2_bf16(float lo, float hi) {
    union { __bf16 b; unsigned short s; } a, c;
    a.b = (__bf16)lo; c.b = (__bf16)hi;
    return (unsigned)a.s | ((unsigned)c.s << 16);
}

// ---------------- fp32 -> bf16 convert (vectorized x4) ----------------
__global__ void cvt_kernel(const float* __restrict__ src, __bf16* __restrict__ dst, int n4) {
    int i = blockIdx.x * blockDim.x + threadIdx.x;
    if (i < n4) {
        float4 v = reinterpret_cast<const float4*>(src)[i];
        bf16x4 o;
        o[0] = (__bf16)v.x; o[1] = (__bf16)v.y; o[2] = (__bf16)v.z; o[3] = (__bf16)v.w;
        reinterpret_cast<bf16x4*>(dst)[i] = o;
    }
}

// ---------------- input projection -> xp stored [T,B,H] ----------------
// 32 bt-rows x 128 cols per block, 8 waves, 2 row-subtiles per wave.
__global__ __launch_bounds__(512) void proj_kernel(const __bf16* __restrict__ x,
                                                   const __bf16* __restrict__ wih,
                                                   const float* __restrict__ bih,
                                                   __bf16* __restrict__ xp) {
    const int m0   = blockIdx.x * 32;      // bt row tile
    const int n0   = blockIdx.y * 128;
    const int lane = threadIdx.x & 63;
    const int wave = threadIdx.x >> 6;     // 0..7
    const int lm   = lane & 15;
    const int quad = lane >> 4;
    const int nw   = n0 + wave * 16;

    f32x4 acc0 = {0.f, 0.f, 0.f, 0.f};
    f32x4 acc1 = {0.f, 0.f, 0.f, 0.f};
    const __bf16* arow0 = x   + (size_t)(m0 + lm) * I_SZ + quad * 8;
    const __bf16* arow1 = arow0 + 16 * I_SZ;
    const __bf16* brow  = wih + (size_t)(nw + lm) * I_SZ + quad * 8;
#pragma unroll 4
    for (int k = 0; k < I_SZ; k += 32) {
        bf16x8 b  = *reinterpret_cast<const bf16x8*>(brow  + k);
        bf16x8 a0 = *reinterpret_cast<const bf16x8*>(arow0 + k);
        bf16x8 a1 = *reinterpret_cast<const bf16x8*>(arow1 + k);
        acc0 = __builtin_amdgcn_mfma_f32_16x16x32_bf16(a0, b, acc0, 0, 0, 0);
        acc1 = __builtin_amdgcn_mfma_f32_16x16x32_bf16(a1, b, acc1, 0, 0, 0);
    }
    const int col  = nw + lm;
    const float bias = bih[col];
#pragma unroll
    for (int r = 0; r < 4; ++r) {
        int row = m0 + quad * 4 + r;       // bt index: b = row>>8, t = row&255
        xp[((size_t)(row & (T_SZ - 1)) * B_SZ + (row >> 8)) * H_SZ + col] = (__bf16)(acc0[r] + bias);
        row += 16;
        xp[((size_t)(row & (T_SZ - 1)) * B_SZ + (row >> 8)) * H_SZ + col] = (__bf16)(acc1[r] + bias);
    }
}

// ---------------- persistent recurrence ----------------
// 64 blocks x 512 threads. block = 16 batch rows x 128 cols, wave = 16 cols.
// group g = bid>>3, chunk cb = bid&7. Epoch-stamped u64 slot exchange.
__global__ __launch_bounds__(THR_P, 2) void rnn_persist(const float* __restrict__ whh,
                                                        const __bf16* __restrict__ xp,
                                                        const float* __restrict__ bhh,
                                                        u64* __restrict__ hbuf,
                                                        float* __restrict__ states,
                                                        float* __restrict__ hlast) {
    __shared__ __align__(16) char lds_raw[16 * PITCH];  // padded-pitch h tile (~32.5 KB)

    const int tid  = threadIdx.x;
    const int lane = tid & 63;
    const int wave = tid >> 6;             // 0..7
    const int lm   = lane & 15;
    const int quad = lane >> 4;
    const int bid  = blockIdx.x;
    const int g    = bid >> 3;             // batch group
    const int cb   = bid & 7;              // col chunk within group
    const int r0   = g * 16;               // first batch row of group
    const int col  = cb * 128 + wave * 16 + lm;

    // ---- W_hh resident (AGPRs): 16 cols x K=1024 per wave, fp32->bf16 inline ----
    bf16x8 wfrag[32];
    {
        const float* wp = whh + (size_t)col * H_SZ + quad * 8;
#pragma unroll
        for (int i = 0; i < 32; ++i) {
            f32x4 lo = *reinterpret_cast<const f32x4*>(wp + i * 32);
            f32x4 hi = *reinterpret_cast<const f32x4*>(wp + i * 32 + 4);
            bf16x8 o;
            o[0] = (__bf16)lo[0]; o[1] = (__bf16)lo[1];
            o[2] = (__bf16)lo[2]; o[3] = (__bf16)lo[3];
            o[4] = (__bf16)hi[0]; o[5] = (__bf16)hi[1];
            o[6] = (__bf16)hi[2]; o[7] = (__bf16)hi[3];
            wfrag[i] = o;
        }
    }
    const float bias = bhh[col];

    u64* buf0 = hbuf;
    u64* buf1 = hbuf + BUF_U64;
    const int oddl = lane & 1;
    const int c2   = wave * 8 + (lm >> 1); // col-pair within 128-col chunk (0..63)
    const int rl0  = oddl ? 2 : 0;         // local rows this lane stores

    size_t st_base[4];
#pragma unroll
    for (int r = 0; r < 4; ++r)
        st_base[r] = (size_t)(r0 + quad * 4 + r) * T_SZ * H_SZ + col;

    for (int t = 0; t < T_SZ; ++t) {
        f32x4 acc0 = {0.f, 0.f, 0.f, 0.f};
        f32x4 acc1 = {0.f, 0.f, 0.f, 0.f};
        float xv[4];

        if (t) {
            // ---- issue all 16 stamped loads (the spin load IS the h load) ----
            const u64* src = ((t & 1) ? buf1 : buf0) + (size_t)g * SLOTS_PER_GROUP + tid;
            u64 v[16];
#pragma unroll
            for (int i = 0; i < 16; ++i)
                v[i] = __hip_atomic_load(src + i * THR_P,
                                         __ATOMIC_RELAXED, __HIP_MEMORY_SCOPE_AGENT);

            // xp loads queued behind the slot loads
#pragma unroll
            for (int r = 0; r < 4; ++r)
                xv[r] = (float)xp[(size_t)t * B_SZ * H_SZ
                                  + (size_t)(r0 + quad * 4 + r) * H_SZ + col];

            // WAR barrier (prev step's ds_reads done) overlaps the load flight
            __syncthreads();

            // ---- pass 0: scatter fresh slots, collect stale mask ----
            unsigned mask = 0;
#pragma unroll
            for (int i = 0; i < 16; ++i) {
                int idx = tid + i * THR_P;     // 0..8191 group slot index
                int p   = idx >> 10;           // chunk 0..7
                int s   = idx & 1023;
                int r   = s >> 6;              // row 0..15
                int cc  = s & 63;              // col-pair 0..63
                if ((unsigned)(v[i] >> 32) == (unsigned)t)
                    *(unsigned*)(lds_raw + r * PITCH + p * 256 + cc * 4) = (unsigned)v[i];
                else
                    mask |= 1u << i;
            }

            // ---- throttled batched retry sweeps ----
            while (__any(mask)) {
                __builtin_amdgcn_s_sleep(1);
#pragma unroll
                for (int i = 0; i < 16; ++i) {
                    if (mask & (1u << i)) {
                        u64 nv = __hip_atomic_load(src + i * THR_P,
                                                   __ATOMIC_RELAXED, __HIP_MEMORY_SCOPE_AGENT);
                        if ((unsigned)(nv >> 32) == (unsigned)t) {
                            int idx = tid + i * THR_P;
                            int p   = idx >> 10;
                            int s   = idx & 1023;
                            int r   = s >> 6;
                            int cc  = s & 63;
                            *(unsigned*)(lds_raw + r * PITCH + p * 256 + cc * 4) = (unsigned)nv;
                            mask &= ~(1u << i);
                        }
                    }
                }
            }
            __syncthreads();

            // ---- MFMA: 16 rows x 16 cols, K=1024, W resident, 2 acc chains ----
#pragma unroll
            for (int i = 0; i < 32; i += 2) {
                bf16x8 a0 = *reinterpret_cast<const bf16x8*>(
                    lds_raw + lm * PITCH + i * 64 + quad * 16);
                bf16x8 a1 = *reinterpret_cast<const bf16x8*>(
                    lds_raw + lm * PITCH + (i + 1) * 64 + quad * 16);
                acc0 = __builtin_amdgcn_mfma_f32_16x16x32_bf16(a0, wfrag[i],     acc0, 0, 0, 0);
                acc1 = __builtin_amdgcn_mfma_f32_16x16x32_bf16(a1, wfrag[i + 1], acc1, 0, 0, 0);
            }
        } else {
#pragma unroll
            for (int r = 0; r < 4; ++r)
                xv[r] = (float)xp[(size_t)(r0 + quad * 4 + r) * H_SZ + col];
        }

        // ---- tanh ----
        float hv[4];
#pragma unroll
        for (int r = 0; r < 4; ++r)
            hv[r] = fast_tanh(acc0[r] + acc1[r] + xv[r] + bias);

        // ---- producer: shfl-pack col-pairs, stamped stores FIRST (critical) ----
        if (t < T_SZ - 1) {
            float pv[4];
#pragma unroll
            for (int r = 0; r < 4; ++r) pv[r] = __shfl_xor(hv[r], 1, 64);
            u64* dst = ((t & 1) ? buf0 : buf1)
                     + (size_t)(g * CHUNKS + cb) * SLOTS_PER_CHUNK;
            const u64 stamp = (u64)(unsigned)(t + 1) << 32;
#pragma unroll
            for (int j = 0; j < 2; ++j) {
                int rl = rl0 + j;
                unsigned pk = oddl ? pack2_bf16(pv[rl], hv[rl])
                                   : pack2_bf16(hv[rl], pv[rl]);
                int row = quad * 4 + rl;
                __hip_atomic_store(dst + row * 64 + c2, stamp | (u64)pk,
                                   __ATOMIC_RELAXED, __HIP_MEMORY_SCOPE_AGENT);
            }
        }

        // ---- fp32 outputs (fire-and-forget; latency overlaps next spin) ----
#pragma unroll
        for (int r = 0; r < 4; ++r)
            states[st_base[r] + (size_t)t * H_SZ] = hv[r];
        if (t == T_SZ - 1) {
#pragma unroll
            for (int r = 0; r < 4; ++r)
                hlast[(size_t)(r0 + quad * 4 + r) * H_SZ + col] = hv[r];
        }
    }
}

extern "C" void kernel_launch(void* const* d_in, const int* in_sizes, int n_in,
                              void* d_out, int out_size, void* d_ws, size_t ws_size,
                              hipStream_t stream) {
    const float* x    = (const float*)d_in[0];   // [B,T,I]
    const float* Wih  = (const float*)d_in[1];   // [H,I]
    const float* Whh  = (const float*)d_in[2];   // [H,H]
    const float* bih  = (const float*)d_in[3];   // [H]
    const float* bhh  = (const float*)d_in[4];   // [H]

    float* states = (float*)d_out;                               // [B,T,H]
    float* hlast  = (float*)d_out + (size_t)B_SZ * T_SZ * H_SZ;  // [B,H]

    // workspace carve (bytes), all 16B aligned
    char* w = (char*)d_ws;
    __bf16* x_bf   = (__bf16*)w;  w += (size_t)B_SZ * T_SZ * I_SZ * 2;  // 33.5 MB
    __bf16* wih_bf = (__bf16*)w;  w += (size_t)H_SZ * I_SZ * 2;         // 1 MB
    __bf16* xp_bf  = (__bf16*)w;  w += (size_t)B_SZ * T_SZ * H_SZ * 2;  // 67 MB, [T,B,H]
    u64*    hbuf   = (u64*)w;     w += (size_t)2 * BUF_U64 * 8;         // 1 MB, 2 epoch buffers
    (void)ws_size;

    // converts (W_hh converted inline by rnn_persist)
    {
        int n4 = B_SZ * T_SZ * I_SZ / 4;
        cvt_kernel<<<(n4 + 255) / 256, 256, 0, stream>>>(x, x_bf, n4);
    }
    {
        int n4 = H_SZ * I_SZ / 4;
        cvt_kernel<<<(n4 + 255) / 256, 256, 0, stream>>>(Wih, wih_bf, n4);
    }

    // epoch buffers = 0 ("stamp 0" never matches any t in 1..255)
    hipMemsetAsync(hbuf, 0, (size_t)2 * BUF_U64 * 8, stream);

    // input projection: 32x128 tiles
    {
        dim3 grid(B_SZ * T_SZ / 32, H_SZ / 128);  // (1024, 8)
        proj_kernel<<<grid, 512, 0, stream>>>(x_bf, wih_bf, bih, xp_bf);
    }

    // persistent recurrence: epoch-stamped flag-free exchange
    rnn_persist<<<GRID_P, THR_P, 0, stream>>>(Whh, xp_bf, bhh, hbuf,
                                              states, hlast);
}

// Round 6
// 1120.728 us; speedup vs baseline: 1.9723x; 1.9723x over previous
//
#include <hip/hip_runtime.h>
#include <hip/hip_bf16.h>

// Elman RNN: B=128, T=256, I=512, H=1024
//   Phase 1: xp[b,h] per t  (MFMA GEMM, bf16, 32x128 tiles)
//   Phase 2: ONE persistent kernel (R4 structure, proven 659us), with
//     XCD-LOCAL GROUPS:
//     - group id = bid & 7  ->  with round-robin block->XCD dispatch, all
//       8 blocks of a group land on the SAME XCD. The group's entire h
//       exchange (32KB region + counter) is XCD-private, so agent-scope
//       traffic can be serviced by the local (coherent-within-XCD) L2
//       instead of 4 cross-die MALL round trips per step.
//       (R4 had g=bid>>3: every group spanned all 8 XCDs - worst case.)
//     - 8 independent batch-group chains, per-group barrier fan-in 8.
//     - W_hh resident (AGPRs) via __launch_bounds__(512,2)  [R4-proven].
//     - padded-pitch LDS, conflicts ~1e6  [R4-proven].
//     - states stores after barrier arrive (HBM latency overlaps spin).
// Precision: bf16 inputs, fp32 MFMA accumulate, fp32 tanh, fp32 output.

#define B_SZ 128
#define T_SZ 256
#define I_SZ 512
#define H_SZ 1024

#define GROUPS 8
#define BLK_PG 8                       // blocks per group (128 cols each)
#define GRID_P (GROUPS * BLK_PG)       // 64 persistent blocks
#define THR_P  512                     // 8 waves: 16 cols x K=1024 each
#define PITCH  2080                    // LDS row pitch (2048 + 32 pad)

typedef __bf16 bf16x8 __attribute__((ext_vector_type(8)));
typedef __bf16 bf16x4 __attribute__((ext_vector_type(4)));
typedef float f32x4 __attribute__((ext_vector_type(4)));
typedef unsigned long long u64;

__device__ __forceinline__ float fast_tanh(float x) {
    // exact at +-inf saturation, ~1e-6 abs err; bf16 noise dominates anyway
    return 1.0f - 2.0f / (__expf(2.0f * x) + 1.0f);
}

// ---------------- fp32 -> bf16 convert (vectorized x4) ----------------
__global__ void cvt_kernel(const float* __restrict__ src, __bf16* __restrict__ dst, int n4) {
    int i = blockIdx.x * blockDim.x + threadIdx.x;
    if (i < n4) {
        float4 v = reinterpret_cast<const float4*>(src)[i];
        bf16x4 o;
        o[0] = (__bf16)v.x; o[1] = (__bf16)v.y; o[2] = (__bf16)v.z; o[3] = (__bf16)v.w;
        reinterpret_cast<bf16x4*>(dst)[i] = o;
    }
}

// ---------------- input projection -> xp stored [T,B,H] ----------------
// 32 bt-rows x 128 cols per block, 8 waves, 2 row-subtiles per wave.
__global__ __launch_bounds__(512) void proj_kernel(const __bf16* __restrict__ x,
                                                   const __bf16* __restrict__ wih,
                                                   const float* __restrict__ bih,
                                                   __bf16* __restrict__ xp) {
    const int m0   = blockIdx.x * 32;      // bt row tile
    const int n0   = blockIdx.y * 128;
    const int lane = threadIdx.x & 63;
    const int wave = threadIdx.x >> 6;     // 0..7
    const int lm   = lane & 15;
    const int quad = lane >> 4;
    const int nw   = n0 + wave * 16;

    f32x4 acc0 = {0.f, 0.f, 0.f, 0.f};
    f32x4 acc1 = {0.f, 0.f, 0.f, 0.f};
    const __bf16* arow0 = x   + (size_t)(m0 + lm) * I_SZ + quad * 8;
    const __bf16* arow1 = arow0 + 16 * I_SZ;
    const __bf16* brow  = wih + (size_t)(nw + lm) * I_SZ + quad * 8;
#pragma unroll 4
    for (int k = 0; k < I_SZ; k += 32) {
        bf16x8 b  = *reinterpret_cast<const bf16x8*>(brow  + k);
        bf16x8 a0 = *reinterpret_cast<const bf16x8*>(arow0 + k);
        bf16x8 a1 = *reinterpret_cast<const bf16x8*>(arow1 + k);
        acc0 = __builtin_amdgcn_mfma_f32_16x16x32_bf16(a0, b, acc0, 0, 0, 0);
        acc1 = __builtin_amdgcn_mfma_f32_16x16x32_bf16(a1, b, acc1, 0, 0, 0);
    }
    const int col  = nw + lm;
    const float bias = bih[col];
#pragma unroll
    for (int r = 0; r < 4; ++r) {
        int row = m0 + quad * 4 + r;       // bt index: b = row>>8, t = row&255
        xp[((size_t)(row & (T_SZ - 1)) * B_SZ + (row >> 8)) * H_SZ + col] = (__bf16)(acc0[r] + bias);
        row += 16;
        xp[((size_t)(row & (T_SZ - 1)) * B_SZ + (row >> 8)) * H_SZ + col] = (__bf16)(acc1[r] + bias);
    }
}

// ---------------- persistent recurrence ----------------
// 64 blocks x 512 threads. block = 16 batch rows x 128 cols, wave = 16 cols.
// group g = bid&7 (XCD-local!), chunk cb = bid>>3. Fan-in-8 counter barrier.
__global__ __launch_bounds__(THR_P, 2) void rnn_persist(const float* __restrict__ whh,
                                                        const __bf16* __restrict__ xp,
                                                        const float* __restrict__ bhh,
                                                        __bf16* __restrict__ hA,
                                                        __bf16* __restrict__ hB,
                                                        float* __restrict__ states,
                                                        float* __restrict__ hlast,
                                                        unsigned* __restrict__ cnt) {
    __shared__ __align__(16) char   lds_raw[16 * PITCH];  // padded-pitch h tile (~32.5 KB)
    __shared__ __align__(16) __bf16 htile[16 * 128];      // 4 KB packed next-h

    const int tid  = threadIdx.x;
    const int lane = tid & 63;
    const int wave = tid >> 6;             // 0..7
    const int lm   = lane & 15;
    const int quad = lane >> 4;
    const int bid  = blockIdx.x;
    const int g    = bid & 7;              // batch group == XCD (round-robin dispatch)
    const int cb   = bid >> 3;             // col chunk within group
    const int r0   = g * 16;               // first batch row of group
    const int col  = cb * 128 + wave * 16 + lm;

    // ---- W_hh resident in VGPRs/AGPRs: 16 cols x K=1024 per wave, fp32->bf16 ----
    bf16x8 wfrag[32];
    {
        const float* wp = whh + (size_t)col * H_SZ + quad * 8;
#pragma unroll
        for (int i = 0; i < 32; ++i) {
            f32x4 lo = *reinterpret_cast<const f32x4*>(wp + i * 32);
            f32x4 hi = *reinterpret_cast<const f32x4*>(wp + i * 32 + 4);
            bf16x8 o;
            o[0] = (__bf16)lo[0]; o[1] = (__bf16)lo[1];
            o[2] = (__bf16)lo[2]; o[3] = (__bf16)lo[3];
            o[4] = (__bf16)hi[0]; o[5] = (__bf16)hi[1];
            o[6] = (__bf16)hi[2]; o[7] = (__bf16)hi[3];
            wfrag[i] = o;
        }
    }
    const float bias = bhh[col];
    unsigned* my_cnt = cnt + g * 32;       // per-group counter, 128B apart

    size_t st_base[4];
#pragma unroll
    for (int r = 0; r < 4; ++r)
        st_base[r] = (size_t)(r0 + quad * 4 + r) * T_SZ * H_SZ + col;

    for (int t = 0; t < T_SZ; ++t) {
        const __bf16* cur = (t & 1) ? hB : hA;
        __bf16*       nxt = (t & 1) ? hA : hB;

        // ---- cooperative h load FIRST (critical path): 32 KB via 8B atomics ----
        const u64* src = (const u64*)(cur + (size_t)r0 * H_SZ);
        u64 v[8];
#pragma unroll
        for (int i = 0; i < 8; ++i)
            v[i] = __hip_atomic_load(src + tid + i * THR_P,
                                     __ATOMIC_RELAXED, __HIP_MEMORY_SCOPE_AGENT);

        // ---- xp loads (off critical path, queued behind h) ----
        float xv[4];
#pragma unroll
        for (int r = 0; r < 4; ++r)
            xv[r] = (float)xp[(size_t)t * B_SZ * H_SZ
                              + (size_t)(r0 + quad * 4 + r) * H_SZ + col];

        // ---- scatter to padded-pitch LDS (prev step's reads done pre-barrier) ----
#pragma unroll
        for (int i = 0; i < 8; ++i) {
            int u   = tid + i * THR_P;     // 0..4095
            int row = u >> 8;              // 256 u64 per 2048B logical row
            int kb  = (u & 255) * 8;       // byte offset in row
            *(u64*)(lds_raw + row * PITCH + kb) = v[i];
        }
        __syncthreads();

        // ---- MFMA: 16 rows x 16 cols, K=1024, W resident, 2 acc chains ----
        f32x4 acc0 = {0.f, 0.f, 0.f, 0.f};
        f32x4 acc1 = {0.f, 0.f, 0.f, 0.f};
#pragma unroll
        for (int i = 0; i < 32; i += 2) {
            bf16x8 a0 = *reinterpret_cast<const bf16x8*>(
                lds_raw + lm * PITCH + i * 64 + quad * 16);
            bf16x8 a1 = *reinterpret_cast<const bf16x8*>(
                lds_raw + lm * PITCH + (i + 1) * 64 + quad * 16);
            acc0 = __builtin_amdgcn_mfma_f32_16x16x32_bf16(a0, wfrag[i],     acc0, 0, 0, 0);
            acc1 = __builtin_amdgcn_mfma_f32_16x16x32_bf16(a1, wfrag[i + 1], acc1, 0, 0, 0);
        }

        // ---- tanh + pack next-h tile into LDS ----
        float hv[4];
#pragma unroll
        for (int r = 0; r < 4; ++r) {
            hv[r] = fast_tanh(acc0[r] + acc1[r] + xv[r] + bias);
            htile[(quad * 4 + r) * 128 + (wave * 16 + lm)] = (__bf16)hv[r];
        }
        __syncthreads();

        if (t < T_SZ - 1) {
            // ---- distributed packed h store: one u64 per thread (4 KB) ----
            {
                int row = tid >> 5;        // 32 u64 per 128-col row
                int c8  = tid & 31;
                __hip_atomic_store((u64*)((char*)nxt + (size_t)(r0 + row) * 2048
                                          + cb * 256 + c8 * 8),
                                   ((const u64*)htile)[tid],
                                   __ATOMIC_RELAXED, __HIP_MEMORY_SCOPE_AGENT);
            }
            __syncthreads();               // vmcnt(0) drain before the arrive
            if (tid == 0)
                __hip_atomic_fetch_add(my_cnt, 1u,
                                       __ATOMIC_RELAXED, __HIP_MEMORY_SCOPE_AGENT);
        }

        // ---- fp32 outputs AFTER arrive: HBM latency overlaps the spin ----
#pragma unroll
        for (int r = 0; r < 4; ++r)
            states[st_base[r] + (size_t)t * H_SZ] = hv[r];
        if (t == T_SZ - 1) {
#pragma unroll
            for (int r = 0; r < 4; ++r)
                hlast[(size_t)(r0 + quad * 4 + r) * H_SZ + col] = hv[r];
        }

        if (t < T_SZ - 1) {
            if (tid == 0) {
                const unsigned target = (unsigned)BLK_PG * (unsigned)(t + 1);
                while (__hip_atomic_load(my_cnt, __ATOMIC_RELAXED,
                                         __HIP_MEMORY_SCOPE_AGENT) < target)
                    __builtin_amdgcn_s_sleep(2);
            }
            __syncthreads();
        }
    }
}

extern "C" void kernel_launch(void* const* d_in, const int* in_sizes, int n_in,
                              void* d_out, int out_size, void* d_ws, size_t ws_size,
                              hipStream_t stream) {
    const float* x    = (const float*)d_in[0];   // [B,T,I]
    const float* Wih  = (const float*)d_in[1];   // [H,I]
    const float* Whh  = (const float*)d_in[2];   // [H,H]
    const float* bih  = (const float*)d_in[3];   // [H]
    const float* bhh  = (const float*)d_in[4];   // [H]

    float* states = (float*)d_out;                               // [B,T,H]
    float* hlast  = (float*)d_out + (size_t)B_SZ * T_SZ * H_SZ;  // [B,H]

    // workspace carve (bytes), all 16B aligned
    char* w = (char*)d_ws;
    __bf16* x_bf   = (__bf16*)w;  w += (size_t)B_SZ * T_SZ * I_SZ * 2;  // 33.5 MB
    __bf16* wih_bf = (__bf16*)w;  w += (size_t)H_SZ * I_SZ * 2;         // 1 MB
    __bf16* xp_bf  = (__bf16*)w;  w += (size_t)B_SZ * T_SZ * H_SZ * 2;  // 67 MB, [T,B,H]
    __bf16* hA     = (__bf16*)w;  w += (size_t)B_SZ * H_SZ * 2;         // 256 KB
    __bf16* hB     = (__bf16*)w;  w += (size_t)B_SZ * H_SZ * 2;         // 256 KB
    unsigned* cnt  = (unsigned*)w; w += 1024;                           // 8 group counters, 128B apart
    (void)ws_size;

    // converts (W_hh converted inline by rnn_persist)
    {
        int n4 = B_SZ * T_SZ * I_SZ / 4;
        cvt_kernel<<<(n4 + 255) / 256, 256, 0, stream>>>(x, x_bf, n4);
    }
    {
        int n4 = H_SZ * I_SZ / 4;
        cvt_kernel<<<(n4 + 255) / 256, 256, 0, stream>>>(Wih, wih_bf, n4);
    }

    // h0 = 0, group counters = 0 (ws is re-poisoned 0xAA before every launch)
    hipMemsetAsync(hA, 0, (size_t)B_SZ * H_SZ * 2, stream);
    hipMemsetAsync(cnt, 0, 1024, stream);

    // input projection: 32x128 tiles
    {
        dim3 grid(B_SZ * T_SZ / 32, H_SZ / 128);  // (1024, 8)
        proj_kernel<<<grid, 512, 0, stream>>>(x_bf, wih_bf, bih, xp_bf);
    }

    // persistent recurrence: 8 XCD-local group chains, fan-in 8 barriers
    rnn_persist<<<GRID_P, THR_P, 0, stream>>>(Whh, xp_bf, bhh, hA, hB,
                                              states, hlast, cnt);
}